// Round 15
// baseline (637.059 us; speedup 1.0000x reference)
//
#include <hip/hip_runtime.h>
#include <hip/hip_bf16.h>
#include <math.h>

// ---------------------------------------------------------------------------
// ResidualAttentionBlock (CLIP + AIM adapters), bf16-MFMA implementation.
// x: (197, 64, 768) fp32. b=8, T=8. Output fp32 same shape.
// ---------------------------------------------------------------------------

typedef __attribute__((ext_vector_type(8))) short bf16x8;
typedef __attribute__((ext_vector_type(4))) float f32x4;

__device__ __forceinline__ float bf2f(short s) {
  unsigned u = ((unsigned)(unsigned short)s) << 16;
  float f;
  __builtin_memcpy(&f, &u, 4);
  return f;
}
__device__ __forceinline__ short f2bf(float f) {
  __hip_bfloat16 h = __float2bfloat16(f);
  short s;
  __builtin_memcpy(&s, &h, 2);
  return s;
}

// async global->LDS, 16B per lane. lds ptr must be wave-uniform base.
__device__ __forceinline__ void gld16(void* lds, const void* g) {
  __builtin_amdgcn_global_load_lds(
      (const __attribute__((address_space(1))) unsigned int*)g,
      (__attribute__((address_space(3))) unsigned int*)lds, 16, 0, 0);
}

// ---------------------------------------------------------------------------
// Weight fp32 -> bf16 conversion (10 arrays in one kernel)
// ---------------------------------------------------------------------------
struct WPair { const float* s; short* d; int n; };
struct WArr { WPair p[10]; };

__global__ __launch_bounds__(256)
void convert_k(WArr a) {
  WPair w = a.p[blockIdx.y];
  for (int i = blockIdx.x * 256 + threadIdx.x; i < w.n; i += gridDim.x * 256)
    w.d[i] = f2bf(w.s[i]);
}

// ---------------------------------------------------------------------------
// LayerNorm (per-token, 768): fp32 in -> bf16 out
// ---------------------------------------------------------------------------
__global__ __launch_bounds__(256)
void ln_k(const float* __restrict__ in, const float* __restrict__ g,
          const float* __restrict__ b, short* __restrict__ out) {
  const int t = blockIdx.x;
  const float* xr = in + (size_t)t * 768;
  const int tid = threadIdx.x;
  float v0 = xr[tid], v1 = xr[tid + 256], v2 = xr[tid + 512];
  float s = v0 + v1 + v2;
#pragma unroll
  for (int m = 1; m < 64; m <<= 1) s += __shfl_xor(s, m);
  __shared__ float red[4];
  if ((tid & 63) == 0) red[tid >> 6] = s;
  __syncthreads();
  float mu = (red[0] + red[1] + red[2] + red[3]) * (1.f / 768.f);
  __syncthreads();
  float d0 = v0 - mu, d1 = v1 - mu, d2 = v2 - mu;
  float q = d0 * d0 + d1 * d1 + d2 * d2;
#pragma unroll
  for (int m = 1; m < 64; m <<= 1) q += __shfl_xor(q, m);
  if ((tid & 63) == 0) red[tid >> 6] = q;
  __syncthreads();
  float rstd = rsqrtf((red[0] + red[1] + red[2] + red[3]) * (1.f / 768.f) + 1e-5f);
  size_t o = (size_t)t * 768;
  out[o + tid]       = f2bf(d0 * rstd * g[tid]       + b[tid]);
  out[o + tid + 256] = f2bf(d1 * rstd * g[tid + 256] + b[tid + 256]);
  out[o + tid + 512] = f2bf(d2 * rstd * g[tid + 512] + b[tid + 512]);
}

// ---------------------------------------------------------------------------
// Small-matrix GEMM (64x64 tiles): C = act(A @ W^T + bias), epilogues as below.
// ACT: 0 none, 1 QuickGELU, 2 exact GELU
// EPI: 0 bf16 out; 1 f32 out; 5 bf16 out = v*lam[row]
// ---------------------------------------------------------------------------
template <int ACT, int EPI>
__global__ __launch_bounds__(256)
void gemm_k(const short* __restrict__ A, int lda,
            const short* __restrict__ W,
            const float* __restrict__ bias,
            short* __restrict__ outb, float* __restrict__ outf,
            const float* __restrict__ lam,
            int M, int N, int K) {
  __shared__ short As[64][40];
  __shared__ short Ws[64][40];
  const int tid = threadIdx.x;
  const int n0 = blockIdx.x * 64;
  const int m0 = blockIdx.y * 64;
  const int lane = tid & 63, w = tid >> 6;
  const int wr = w >> 1, wc = w & 1;
  const int g = lane >> 4, li = lane & 15;
  const int srow = tid >> 2, scol = (tid & 3) * 8;

  f32x4 acc[2][2];
#pragma unroll
  for (int i = 0; i < 2; i++)
#pragma unroll
    for (int j = 0; j < 2; j++) acc[i][j] = (f32x4){0.f, 0.f, 0.f, 0.f};

  const short* Aptr = A + (size_t)(m0 + srow) * lda + scol;
  const short* Wptr = W + (size_t)(n0 + srow) * K + scol;

  for (int kk = 0; kk < K; kk += 32) {
    __syncthreads();
    *(bf16x8*)&As[srow][scol] = *(const bf16x8*)(Aptr + kk);
    *(bf16x8*)&Ws[srow][scol] = *(const bf16x8*)(Wptr + kk);
    __syncthreads();
    bf16x8 a[2], b[2];
#pragma unroll
    for (int mi = 0; mi < 2; ++mi)
      a[mi] = *(const bf16x8*)&As[wr * 32 + mi * 16 + li][g * 8];
#pragma unroll
    for (int ni = 0; ni < 2; ++ni)
      b[ni] = *(const bf16x8*)&Ws[wc * 32 + ni * 16 + li][g * 8];
#pragma unroll
    for (int mi = 0; mi < 2; ++mi)
#pragma unroll
      for (int ni = 0; ni < 2; ++ni)
        acc[mi][ni] = __builtin_amdgcn_mfma_f32_16x16x32_bf16(
            a[mi], b[ni], acc[mi][ni], 0, 0, 0);
  }

#pragma unroll
  for (int mi = 0; mi < 2; ++mi)
#pragma unroll
    for (int ni = 0; ni < 2; ++ni)
#pragma unroll
      for (int r = 0; r < 4; ++r) {
        int row = m0 + wr * 32 + mi * 16 + g * 4 + r;
        int col = n0 + wc * 32 + ni * 16 + li;
        float v = acc[mi][ni][r];
        if (bias) v += bias[col];
        if (ACT == 1) v = v / (1.f + __expf(-1.702f * v));
        if (ACT == 2) v = 0.5f * v * (1.f + erff(v * 0.70710678118f));
        size_t idx = (size_t)row * N + col;
        if (EPI == 0) outb[idx] = f2bf(v);
        else if (EPI == 1) outf[idx] = v;
        else if (EPI == 5) outb[idx] = f2bf(v * lam[row]);
      }
}

// ---------------------------------------------------------------------------
// Wide GEMM, 8 waves, 256x128 tile (4M x 2N wave grid, each wave 64x64,
// acc[4][4] -> 16 MFMA per K-step). BK=32, 3-buffer ring (A 48 KB + W 24 KB
// = 72 KB; launch_bounds(512,4) already caps at 2 blocks/CU so the extra
// buffer is occupancy-free). 2-tile-deep prefetch: STAGE(t+2) issued, then
// counted vmcnt(3) for tile t — loads get ~2 step-times (~740 cyc) to land
// vs R14's 1 step (~370 cyc) against ~900 cyc latency. Tail 3->0.
// Conflict-free XOR swizzle + XCD swizzle. For grid-rich GEMMs (qkv, fc).
// ACT: 0 none, 1 QuickGELU. Output bf16.
// ---------------------------------------------------------------------------
template <int ACT>
__global__ __launch_bounds__(512, 4)
void gemm256x128_k(const short* __restrict__ A, int lda,
                   const short* __restrict__ W,
                   const float* __restrict__ bias,
                   short* __restrict__ outb,
                   int M, int N, int K, int nx) {
  int nwg = gridDim.x;
  int orig = blockIdx.x;
  int q = nwg >> 3, r = nwg & 7;
  int xcd = orig & 7, cidx = orig >> 3;
  int wgid = (xcd < r ? xcd * (q + 1) : r * (q + 1) + (xcd - r) * q) + cidx;
  const int n0 = (wgid % nx) * 128;
  const int m0 = (wgid / nx) * 256;

  __shared__ short As[3][256][32];   // 48 KB
  __shared__ short Ws[3][128][32];   // 24 KB
  const int tid = threadIdx.x;
  const int w = tid >> 6, lane = tid & 63;
  const int g = lane >> 4, li = lane & 15;
  const int wr = w >> 1, wc = w & 1;     // 4M x 2N wave grid

  const int sgc = ((tid & 3) ^ ((tid >> 3) & 3)) * 8;   // pre-swizzled src chunk
  const int cxr = (g ^ ((li >> 1) & 3)) * 8;            // swizzled read chunk

  f32x4 acc[4][4];
#pragma unroll
  for (int i = 0; i < 4; i++)
#pragma unroll
    for (int j = 0; j < 4; j++) acc[i][j] = (f32x4){0.f, 0.f, 0.f, 0.f};

  int arj[2];
#pragma unroll
  for (int j = 0; j < 2; ++j) {
    int rA = m0 + j * 128 + (tid >> 2);
    arj[j] = rA > M - 1 ? M - 1 : rA;
  }
  const short* Ap0 = A + (size_t)arj[0] * lda + sgc;
  const short* Ap1 = A + (size_t)arj[1] * lda + sgc;
  const short* Wp  = W + (size_t)(n0 + (tid >> 2)) * K + sgc;

  const int total = K >> 5;

  auto STAGE = [&](int s, int bi) {
    const int kk = s * 32;
    gld16(&As[bi][w * 16][0],       Ap0 + kk);
    gld16(&As[bi][128 + w * 16][0], Ap1 + kk);
    gld16(&Ws[bi][w * 16][0],       Wp + kk);
  };

  // prologue: 2 tiles in flight
  STAGE(0, 0);
  if (total > 1) STAGE(1, 1);

  int bi = 0, pb = 2;
  for (int t = 0; t < total; ++t) {
    const int rem = total - 1 - t;
    if (t + 2 < total) STAGE(t + 2, pb);        // deepen before waiting
    if (rem >= 2)
      asm volatile("s_waitcnt vmcnt(6)" ::: "memory");   // tile t landed (2 ahead)
    else if (rem == 1)
      asm volatile("s_waitcnt vmcnt(3)" ::: "memory");
    else
      asm volatile("s_waitcnt vmcnt(0)" ::: "memory");
    __builtin_amdgcn_s_barrier();

    bf16x8 a[4], b[4];
#pragma unroll
    for (int mi = 0; mi < 4; ++mi)
      a[mi] = *(const bf16x8*)&As[bi][wr * 64 + mi * 16 + li][cxr];
#pragma unroll
    for (int ni = 0; ni < 4; ++ni)
      b[ni] = *(const bf16x8*)&Ws[bi][wc * 64 + ni * 16 + li][cxr];
    asm volatile("s_waitcnt lgkmcnt(0)" ::: "memory");
    __builtin_amdgcn_sched_barrier(0);
#pragma unroll
    for (int mi = 0; mi < 4; ++mi)
#pragma unroll
      for (int ni = 0; ni < 4; ++ni)
        acc[mi][ni] = __builtin_amdgcn_mfma_f32_16x16x32_bf16(
            a[mi], b[ni], acc[mi][ni], 0, 0, 0);
    __builtin_amdgcn_s_barrier();

    bi = bi + 1; if (bi == 3) bi = 0;
    pb = pb + 1; if (pb == 3) pb = 0;
  }

#pragma unroll
  for (int mi = 0; mi < 4; ++mi)
#pragma unroll
    for (int ni = 0; ni < 4; ++ni)
#pragma unroll
      for (int r = 0; r < 4; ++r) {
        int row = m0 + wr * 64 + mi * 16 + g * 4 + r;
        int col = n0 + wc * 64 + ni * 16 + li;
        if (row >= M) continue;
        float v = acc[mi][ni][r];
        if (bias) v += bias[col];
        if (ACT == 1) v = v / (1.f + __expf(-1.702f * v));
        outb[(size_t)row * N + col] = f2bf(v);
      }
}

// ---------------------------------------------------------------------------
// Big GEMM, 8-wave pipeline: 128x128 tile, 512 threads (2M x 4N, each wave
// 64x32 -> acc[4][2]), BK=32, 3-buffer ring (48 KB -> 3 blocks/CU, matching
// the (512,6) reg cap exactly). 2-tile-deep prefetch, counted vmcnt(4)/(2)/0.
// Conflict-free XOR swizzle + XCD grid swizzle. Optional second GEMM.
// For grid-starved N=768 GEMMs (x1, proj: 594 blocks).
// EPI: 0 bf16 out; 2 x1 = resid + (1-lam[n])*v + addv; 6 f32 out = resid + v
// ---------------------------------------------------------------------------
template <int ACT, int EPI>
__global__ __launch_bounds__(512, 6)
void gemm512_k(const short* __restrict__ A, int lda,
               const short* __restrict__ W,
               const float* __restrict__ bias,
               short* __restrict__ outb, float* __restrict__ outf,
               const float* __restrict__ lam,
               const float* __restrict__ addv,
               const float* __restrict__ resid,
               const short* __restrict__ A2, int lda2,
               const short* __restrict__ W2,
               const float* __restrict__ bias2, int K2,
               int M, int N, int K, int nx) {
  int nwg = gridDim.x;
  int orig = blockIdx.x;
  int q = nwg >> 3, r = nwg & 7;
  int xcd = orig & 7, cidx = orig >> 3;
  int wgid = (xcd < r ? xcd * (q + 1) : r * (q + 1) + (xcd - r) * q) + cidx;
  const int n0 = (wgid % nx) * 128;
  const int m0 = (wgid / nx) * 128;

  __shared__ short As[3][128][32];   // 24 KB
  __shared__ short Ws[3][128][32];   // 24 KB
  const int tid = threadIdx.x;
  const int w = tid >> 6, lane = tid & 63;
  const int g = lane >> 4, li = lane & 15;
  const int wr = w >> 2, wc = w & 3;          // 2M x 4N wave grid

  const int srow = tid >> 2;                                  // 0..127
  const int scol = ((tid & 3) ^ ((tid >> 3) & 3)) * 8;        // pre-swizzled src
  const int cxr  = (g ^ ((li >> 1) & 3)) * 8;                 // swizzled read

  f32x4 acc[4][2];
#pragma unroll
  for (int i = 0; i < 4; i++)
#pragma unroll
    for (int j = 0; j < 2; j++) acc[i][j] = (f32x4){0.f, 0.f, 0.f, 0.f};

  int ar = m0 + srow; if (ar > M - 1) ar = M - 1;
  const short* Ap = A + (size_t)ar * lda + scol;
  const short* Wp = W + (size_t)(n0 + srow) * K + scol;
  const short* A2b = A2 ? A2 : A;
  const short* W2b = W2 ? W2 : W;
  const short* Bp = A2b + (size_t)ar * lda2 + scol;
  const short* Vp = W2b + (size_t)(n0 + srow) * K2 + scol;

  const int ks1 = K >> 5;
  const int ks2 = A2 ? (K2 >> 5) : 0;
  const int total = ks1 + ks2;

  auto STAGE = [&](int s, int bi) {
    if (s < ks1) {
      const int kk = s * 32;
      gld16(&As[bi][w * 16][0], Ap + kk);
      gld16(&Ws[bi][w * 16][0], Wp + kk);
    } else {
      const int kk = (s - ks1) * 32;
      gld16(&As[bi][w * 16][0], Bp + kk);
      gld16(&Ws[bi][w * 16][0], Vp + kk);
    }
  };

  STAGE(0, 0);
  if (total > 1) STAGE(1, 1);

  int bi = 0, pb = 2;
  for (int t = 0; t < total; ++t) {
    const int rem = total - 1 - t;
    if (t + 2 < total) STAGE(t + 2, pb);
    if (rem >= 2)
      asm volatile("s_waitcnt vmcnt(4)" ::: "memory");
    else if (rem == 1)
      asm volatile("s_waitcnt vmcnt(2)" ::: "memory");
    else
      asm volatile("s_waitcnt vmcnt(0)" ::: "memory");
    __builtin_amdgcn_s_barrier();

    bf16x8 a[4], b[2];
#pragma unroll
    for (int mi = 0; mi < 4; ++mi)
      a[mi] = *(const bf16x8*)&As[bi][wr * 64 + mi * 16 + li][cxr];
#pragma unroll
    for (int ni = 0; ni < 2; ++ni)
      b[ni] = *(const bf16x8*)&Ws[bi][wc * 32 + ni * 16 + li][cxr];
    asm volatile("s_waitcnt lgkmcnt(0)" ::: "memory");
    __builtin_amdgcn_sched_barrier(0);
#pragma unroll
    for (int mi = 0; mi < 4; ++mi)
#pragma unroll
      for (int ni = 0; ni < 2; ++ni)
        acc[mi][ni] = __builtin_amdgcn_mfma_f32_16x16x32_bf16(
            a[mi], b[ni], acc[mi][ni], 0, 0, 0);
    __builtin_amdgcn_s_barrier();

    bi = bi + 1; if (bi == 3) bi = 0;
    pb = pb + 1; if (pb == 3) pb = 0;
  }

#pragma unroll
  for (int mi = 0; mi < 4; ++mi)
#pragma unroll
    for (int ni = 0; ni < 2; ++ni)
#pragma unroll
      for (int r = 0; r < 4; ++r) {
        int row = m0 + wr * 64 + mi * 16 + g * 4 + r;
        int col = n0 + wc * 32 + ni * 16 + li;
        if (row >= M) continue;
        float v = acc[mi][ni][r];
        if (bias) v += bias[col];
        if (bias2) v += bias2[col];
        if (ACT == 1) v = v / (1.f + __expf(-1.702f * v));
        if (ACT == 2) v = 0.5f * v * (1.f + erff(v * 0.70710678118f));
        size_t idx = (size_t)row * N + col;
        if (EPI == 0) outb[idx] = f2bf(v);
        else if (EPI == 2) {
          float l = lam[row & 63];
          outf[idx] = resid[idx] + (1.f - l) * v + addv[(size_t)(row & 63) * 768 + col];
        } else if (EPI == 6) outf[idx] = resid[idx] + v;
      }
}

// ---------------------------------------------------------------------------
// Main attention (per n,h): softmax(Q K^T / 8) V, Tx=Ty=197, hd=64.
// qkv layout: [token = p*64+n][2304], q|k|v at +0,+768,+1536, head h at h*64.
// ---------------------------------------------------------------------------
__global__ __launch_bounds__(256)
void attn_k(const short* __restrict__ qkv, short* __restrict__ attn_out) {
  const int n = blockIdx.x;
  const int h = blockIdx.y;
  const int tid = threadIdx.x;
  const int lane = tid & 63, w = tid >> 6;
  const int g = lane >> 4, li = lane & 15;

  __shared__ short Vt[64][232];       // V^T [d][key], keys 0..223 (zero pad)
  __shared__ short Pl[4][16][232];    // per-wave P tile [qrow][key]

  {
    const int d = tid & 63;
    for (int key = tid >> 6; key < 224; key += 4) {
      short v = 0;
      if (key < 197)
        v = qkv[(size_t)(key * 64 + n) * 2304 + 1536 + h * 64 + d];
      Vt[d][key] = v;
    }
  }
  __syncthreads();

  const short* Qb = qkv + (size_t)n * 2304 + h * 64;
  const short* Kb = Qb + 768;

  for (int mt = w; mt < 13; mt += 4) {
    const int m0 = mt * 16;
    int arow = m0 + li;
    if (arow > 196) arow = 196;
    bf16x8 a0 = *(const bf16x8*)(Qb + (size_t)arow * 147456 + g * 8);
    bf16x8 a1 = *(const bf16x8*)(Qb + (size_t)arow * 147456 + 32 + g * 8);

    float s[13][4];
#pragma unroll
    for (int nt = 0; nt < 13; ++nt) {
      int kc = nt * 16 + li;
      if (kc > 196) kc = 196;
      bf16x8 b0 = *(const bf16x8*)(Kb + (size_t)kc * 147456 + g * 8);
      bf16x8 b1 = *(const bf16x8*)(Kb + (size_t)kc * 147456 + 32 + g * 8);
      f32x4 acc = (f32x4){0.f, 0.f, 0.f, 0.f};
      acc = __builtin_amdgcn_mfma_f32_16x16x32_bf16(a0, b0, acc, 0, 0, 0);
      acc = __builtin_amdgcn_mfma_f32_16x16x32_bf16(a1, b1, acc, 0, 0, 0);
#pragma unroll
      for (int r = 0; r < 4; ++r) s[nt][r] = acc[r] * 0.125f;
    }

    // row-wise softmax (rows live in 16-lane groups; reduce via shfl_xor)
#pragma unroll
    for (int r = 0; r < 4; ++r) {
      float mx = -1e30f;
#pragma unroll
      for (int nt = 0; nt < 13; ++nt) {
        if (nt * 16 + li >= 197) s[nt][r] = -1e30f;
        mx = fmaxf(mx, s[nt][r]);
      }
      mx = fmaxf(mx, __shfl_xor(mx, 1));
      mx = fmaxf(mx, __shfl_xor(mx, 2));
      mx = fmaxf(mx, __shfl_xor(mx, 4));
      mx = fmaxf(mx, __shfl_xor(mx, 8));
      float sum = 0.f;
#pragma unroll
      for (int nt = 0; nt < 13; ++nt) {
        float e = (s[nt][r] <= -1e29f) ? 0.f : __expf(s[nt][r] - mx);
        s[nt][r] = e;
        sum += e;
      }
      sum += __shfl_xor(sum, 1);
      sum += __shfl_xor(sum, 2);
      sum += __shfl_xor(sum, 4);
      sum += __shfl_xor(sum, 8);
      float inv = 1.f / sum;
#pragma unroll
      for (int nt = 0; nt < 13; ++nt) s[nt][r] *= inv;
    }

    // write P tile (bf16) into this wave's LDS region
#pragma unroll
    for (int r = 0; r < 4; ++r) {
      int row = g * 4 + r;
#pragma unroll
      for (int nt = 0; nt < 13; ++nt)
        Pl[w][row][nt * 16 + li] = f2bf(s[nt][r]);
      Pl[w][row][208 + li] = 0;
    }
    asm volatile("s_waitcnt lgkmcnt(0)" ::: "memory");
    __builtin_amdgcn_sched_barrier(0);

    // PV: O(16x64) = P(16x224) @ V(224x64)
    f32x4 o[4];
#pragma unroll
    for (int ni = 0; ni < 4; ++ni) o[ni] = (f32x4){0.f, 0.f, 0.f, 0.f};
#pragma unroll
    for (int kk = 0; kk < 7; ++kk) {
      bf16x8 pa = *(const bf16x8*)&Pl[w][li][kk * 32 + g * 8];
#pragma unroll
      for (int ni = 0; ni < 4; ++ni) {
        bf16x8 vb = *(const bf16x8*)&Vt[ni * 16 + li][kk * 32 + g * 8];
        o[ni] = __builtin_amdgcn_mfma_f32_16x16x32_bf16(pa, vb, o[ni], 0, 0, 0);
      }
    }
#pragma unroll
    for (int ni = 0; ni < 4; ++ni)
#pragma unroll
      for (int r = 0; r < 4; ++r) {
        int prow = m0 + g * 4 + r;
        if (prow < 197)
          attn_out[(size_t)(prow * 64 + n) * 768 + h * 64 + ni * 16 + li] =
              f2bf(o[ni][r]);
      }
  }
}

// ---------------------------------------------------------------------------
// lam partial: block (n, mt) computes sum_{p in tile, k<197} exp((Q_p.K_k)/8)
// over the full 768-dim dot, writes eo_part[n*13+mt]. No atomics.
// ---------------------------------------------------------------------------
__global__ __launch_bounds__(256)
void lam_part_k(const short* __restrict__ qkv, float* __restrict__ eo_part) {
  const int n = blockIdx.x;
  const int mt = blockIdx.y;
  const int tid = threadIdx.x;
  const int lane = tid & 63, w = tid >> 6;
  const int g = lane >> 4, li = lane & 15;
  const short* Qb = qkv + (size_t)n * 2304;
  const short* Kb = Qb + 768;

  int arow = mt * 16 + li;
  if (arow > 196) arow = 196;
  const short* Ap = Qb + (size_t)arow * 147456;

  // hoist A fragments (24 x bf16x8)
  bf16x8 a[24];
#pragma unroll
  for (int s = 0; s < 24; ++s)
    a[s] = *(const bf16x8*)(Ap + s * 32 + g * 8);

  float eo = 0.f;
  for (int nt = w; nt < 13; nt += 4) {
    int kc = nt * 16 + li;
    if (kc > 196) kc = 196;
    const short* Bp = Kb + (size_t)kc * 147456;
    f32x4 acc = (f32x4){0.f, 0.f, 0.f, 0.f};
#pragma unroll
    for (int s = 0; s < 24; ++s) {
      bf16x8 b = *(const bf16x8*)(Bp + s * 32 + g * 8);
      acc = __builtin_amdgcn_mfma_f32_16x16x32_bf16(a[s], b, acc, 0, 0, 0);
    }
#pragma unroll
    for (int r = 0; r < 4; ++r) {
      int prow = mt * 16 + g * 4 + r;
      int col = nt * 16 + li;
      if (prow < 197 && col < 197) eo += __expf(acc[r] * 0.125f);
    }
  }

#pragma unroll
  for (int m = 1; m < 64; m <<= 1) eo += __shfl_xor(eo, m);
  __shared__ float red[4];
  if (lane == 0) red[w] = eo;
  __syncthreads();
  if (tid == 0)
    eo_part[n * 13 + mt] = red[0] + red[1] + red[2] + red[3];
}

// ---------------------------------------------------------------------------
// lam finalize: per n, ec = sum_p exp((Q_p . kt_n)/8); lam = ec/(ec+eo)
// ---------------------------------------------------------------------------
__global__ __launch_bounds__(64)
void lam_fin_k(const short* __restrict__ qkv, const short* __restrict__ kvt,
               const float* __restrict__ eo_part, float* __restrict__ lam) {
  const int n = blockIdx.x;
  const int lane = threadIdx.x;
  const short* kt = kvt + (size_t)n * 1536;

  float ec = 0.f;
  for (int p = lane; p < 197; p += 64) {
    const short* qp = qkv + (size_t)n * 2304 + (size_t)p * 147456;
    float dot = 0.f;
    for (int d0 = 0; d0 < 768; d0 += 8) {
      bf16x8 qa = *(const bf16x8*)(qp + d0);
      bf16x8 ka = *(const bf16x8*)(kt + d0);
#pragma unroll
      for (int j = 0; j < 8; ++j) dot += bf2f(qa[j]) * bf2f(ka[j]);
    }
    ec += __expf(dot * 0.125f);
  }
#pragma unroll
  for (int m = 1; m < 64; m <<= 1) ec += __shfl_xor(ec, m);

  if (lane == 0) {
    float eo = 0.f;
#pragma unroll
    for (int t = 0; t < 13; ++t) eo += eo_part[n * 13 + t];
    lam[n] = ec / (ec + eo);
  }
}

// ---------------------------------------------------------------------------
// Temporal attention on class token: per (bb,h), 8x8 scores over qkv rows 0..63
// ---------------------------------------------------------------------------
__global__ __launch_bounds__(64)
void tattn_k(const short* __restrict__ qkv, short* __restrict__ attn_t) {
  const int bb = blockIdx.x, h = blockIdx.y;
  const int tid = threadIdx.x;
  __shared__ float sm[8][9];
  {
    const int tt = tid >> 3, ss = tid & 7;
    const short* q = qkv + (size_t)(bb * 8 + tt) * 2304 + h * 64;
    const short* k = qkv + (size_t)(bb * 8 + ss) * 2304 + 768 + h * 64;
    float dot = 0.f;
#pragma unroll
    for (int d = 0; d < 64; d += 8) {
      bf16x8 qa = *(const bf16x8*)(q + d);
      bf16x8 ka = *(const bf16x8*)(k + d);
#pragma unroll
      for (int j = 0; j < 8; ++j) dot += bf2f(qa[j]) * bf2f(ka[j]);
    }
    sm[tt][ss] = dot * 0.125f;
  }
  __syncthreads();
  if (tid < 8) {
    float mx = -1e30f;
#pragma unroll
    for (int s2 = 0; s2 < 8; ++s2) mx = fmaxf(mx, sm[tid][s2]);
    float sum = 0.f;
#pragma unroll
    for (int s2 = 0; s2 < 8; ++s2) {
      float e = __expf(sm[tid][s2] - mx);
      sm[tid][s2] = e;
      sum += e;
    }
    float inv = 1.f / sum;
#pragma unroll
    for (int s2 = 0; s2 < 8; ++s2) sm[tid][s2] *= inv;
  }
  __syncthreads();
  {
    const int d = tid;
    float v[8];
#pragma unroll
    for (int s2 = 0; s2 < 8; ++s2)
      v[s2] = bf2f(qkv[(size_t)(bb * 8 + s2) * 2304 + 1536 + h * 64 + d]);
#pragma unroll
    for (int tt = 0; tt < 8; ++tt) {
      float o = 0.f;
#pragma unroll
      for (int s2 = 0; s2 < 8; ++s2) o += sm[tt][s2] * v[s2];
      attn_t[(size_t)(bb * 8 + tt) * 768 + h * 64 + d] = f2bf(o);
    }
  }
}

// ---------------------------------------------------------------------------
// Host launch
// ---------------------------------------------------------------------------
extern "C" void kernel_launch(void* const* d_in, const int* in_sizes, int n_in,
                              void* d_out, int out_size, void* d_ws,
                              size_t ws_size, hipStream_t stream) {
  (void)in_sizes; (void)n_in; (void)out_size; (void)ws_size;

  const float* x          = (const float*)d_in[0];
  const float* in_proj_w  = (const float*)d_in[1];
  const float* in_proj_b  = (const float*)d_in[2];
  const float* out_proj_w = (const float*)d_in[3];
  const float* out_proj_b = (const float*)d_in[4];
  const float* ln1_g      = (const float*)d_in[5];
  const float* ln1_b      = (const float*)d_in[6];
  const float* ln2_g      = (const float*)d_in[7];
  const float* ln2_b      = (const float*)d_in[8];
  const float* fc_w       = (const float*)d_in[9];
  const float* fc_b       = (const float*)d_in[10];
  const float* proj_w     = (const float*)d_in[11];
  const float* proj_b     = (const float*)d_in[12];
  const float* sa1_w      = (const float*)d_in[13];
  const float* sa1_b      = (const float*)d_in[14];
  const float* sa2_w      = (const float*)d_in[15];
  const float* sa2_b      = (const float*)d_in[16];
  const float* ta1_w      = (const float*)d_in[17];
  const float* ta1_b      = (const float*)d_in[18];
  const float* ta2_w      = (const float*)d_in[19];
  const float* ta2_b      = (const float*)d_in[20];
  const float* ma1_w      = (const float*)d_in[21];
  const float* ma1_b      = (const float*)d_in[22];
  const float* ma2_w      = (const float*)d_in[23];
  const float* ma2_b      = (const float*)d_in[24];

  char* ws = (char*)d_ws;
  short* xln  = (short*)(ws + 0);           // 12608x768 bf16
  short* qkv  = (short*)(ws + 19365888);    // 12608x2304 bf16
  short* hbuf = (short*)(ws + 0);           // 12608x3072 bf16 (overlays xln+qkv)
  short* attn = (short*)(ws + 77463552);    // 12608x768 bf16
  short* h2   = (short*)(ws + 77463552);    // 12608x192 bf16 (overlays attn)
  float* x1   = (float*)(ws + 96829440);    // 12608x768 f32
  short* xn   = (short*)(ws + 135561216);   // 12608x768 bf16

  char* wreg = ws + 154927104;
  short* w_inproj  = (short*)(wreg + 0);
  short* w_outproj = (short*)(wreg + 3538944);
  short* w_fc      = (short*)(wreg + 4718592);
  short* w_proj    = (short*)(wreg + 9437184);
  short* w_sa1     = (short*)(wreg + 14155776);
  short* w_sa2     = (short*)(wreg + 14450688);
  short* w_ta1     = (short*)(wreg + 14745600);
  short* w_ta2     = (short*)(wreg + 15040512);
  short* w_ma1     = (short*)(wreg + 15335424);
  short* w_ma2     = (short*)(wreg + 15630336);

  char* sm = ws + 170852352;
  short* attn_t  = (short*)(sm + 0);
  short* tproj   = (short*)(sm + 98304);
  short* th      = (short*)(sm + 196608);
  short* xt_out  = (short*)(sm + 221184);
  short* kv_t    = (short*)(sm + 319488);
  short* a_in    = (short*)(sm + 516096);
  short* sa_h    = (short*)(sm + 614400);
  float* sa_out  = (float*)(sm + 638976);
  float* lam     = (float*)(sm + 835584);
  float* eo_part = (float*)(sm + 835840);   // 64*13 floats

  float* out = (float*)d_out;

  // 0. weights -> bf16
  WArr arr;
  arr.p[0] = {in_proj_w,  w_inproj,  2304 * 768};
  arr.p[1] = {out_proj_w, w_outproj, 768 * 768};
  arr.p[2] = {fc_w,       w_fc,      3072 * 768};
  arr.p[3] = {proj_w,     w_proj,    768 * 3072};
  arr.p[4] = {sa1_w,      w_sa1,     192 * 768};
  arr.p[5] = {sa2_w,      w_sa2,     768 * 192};
  arr.p[6] = {ta1_w,      w_ta1,     192 * 768};
  arr.p[7] = {ta2_w,      w_ta2,     768 * 192};
  arr.p[8] = {ma1_w,      w_ma1,     192 * 768};
  arr.p[9] = {ma2_w,      w_ma2,     768 * 192};
  convert_k<<<dim3(128, 10), 256, 0, stream>>>(arr);

  // 1. LN1(x) -> xln
  ln_k<<<12608, 256, 0, stream>>>(x, ln1_g, ln1_b, xln);

  // 2. qkv = xln @ in_proj^T + b   (12608 x 2304), 256x128 tiles
  gemm256x128_k<0><<<50 * 18, 512, 0, stream>>>(
      xln, 768, w_inproj, in_proj_b, qkv, 12608, 2304, 768, 18);

  // 3. lam partial sums (needs qkv only)
  lam_part_k<<<dim3(64, 13), 256, 0, stream>>>(qkv, eo_part);

  // 4. temporal attention on class token (uses qkv rows 0..63)
  tattn_k<<<dim3(8, 12), 64, 0, stream>>>(qkv, attn_t);

  // 5. tproj = attn_t @ out_proj^T + b
  gemm_k<0, 0><<<dim3(12, 1), 256, 0, stream>>>(
      attn_t, 768, w_outproj, out_proj_b, tproj, nullptr, nullptr, 64, 768, 768);
  // 6. th = gelu(tproj @ ta1^T + b)
  gemm_k<2, 0><<<dim3(3, 1), 256, 0, stream>>>(
      tproj, 768, w_ta1, ta1_b, th, nullptr, nullptr, 64, 192, 768);
  // 7. xt_out = th @ ta2^T + b
  gemm_k<0, 0><<<dim3(12, 1), 256, 0, stream>>>(
      th, 192, w_ta2, ta2_b, xt_out, nullptr, nullptr, 64, 768, 192);
  // 8. kv_t = xt_out @ in_proj[768:2304]^T + b[768:2304]  (64 x 1536)
  gemm_k<0, 0><<<dim3(24, 1), 256, 0, stream>>>(
      xt_out, 768, w_inproj + 768 * 768, in_proj_b + 768, kv_t, nullptr,
      nullptr, 64, 1536, 768);

  // 9. main attention -> attn (pre out-proj)
  attn_k<<<dim3(64, 12), 256, 0, stream>>>(qkv, attn);

  // 10. lam finalize (needs kv_t + eo_part)
  lam_fin_k<<<64, 64, 0, stream>>>(qkv, kv_t, eo_part, lam);

  // 11. a_in = lam * (v_t @ out_proj^T + b)
  gemm_k<0, 5><<<dim3(12, 1), 256, 0, stream>>>(
      kv_t + 768, 1536, w_outproj, out_proj_b, a_in, nullptr, lam, 64, 768, 768);
  // 12. sa_h = gelu(a_in @ sa1^T + b)
  gemm_k<2, 0><<<dim3(3, 1), 256, 0, stream>>>(
      a_in, 768, w_sa1, sa1_b, sa_h, nullptr, nullptr, 64, 192, 768);
  // 13. sa_out = sa_h @ sa2^T + b (f32)
  gemm_k<0, 1><<<dim3(12, 1), 256, 0, stream>>>(
      sa_h, 192, w_sa2, sa2_b, nullptr, sa_out, nullptr, 64, 768, 192);

  // 14. x1 = x + (1-lam)*(attn @ out_proj^T + b) + sa_out[n]
  gemm512_k<0, 2><<<6 * 99, 512, 0, stream>>>(
      attn, 768, w_outproj, out_proj_b, nullptr, x1, lam, sa_out, x,
      nullptr, 0, nullptr, nullptr, 32, 12608, 768, 768, 6);

  // 15. LN2(x1) -> xn
  ln_k<<<12608, 256, 0, stream>>>(x1, ln2_g, ln2_b, xn);

  // 16. h = quickgelu(xn @ fc^T + b)  (12608 x 3072), 256x128 tiles
  gemm256x128_k<1><<<50 * 24, 512, 0, stream>>>(
      xn, 768, w_fc, fc_b, hbuf, 12608, 3072, 768, 24);
  // 17. h2 = gelu(xn @ ma1^T + b)  (12608 x 192)
  gemm_k<2, 0><<<dim3(3, 197), 256, 0, stream>>>(
      xn, 768, w_ma1, ma1_b, h2, nullptr, nullptr, 12608, 192, 768);

  // 18. out = x1 + h @ proj^T + h2 @ ma2^T + proj_b + ma2_b  (fused dual-K)
  gemm512_k<0, 6><<<6 * 99, 512, 0, stream>>>(
      hbuf, 3072, w_proj, proj_b, nullptr, out, nullptr, nullptr, x1,
      h2, 192, w_ma2, ma2_b, 192, 12608, 768, 3072, 6);
}

// Round 17
// 626.449 us; speedup vs baseline: 1.0169x; 1.0169x over previous
//
#include <hip/hip_runtime.h>
#include <hip/hip_bf16.h>
#include <math.h>

// ---------------------------------------------------------------------------
// ResidualAttentionBlock (CLIP + AIM adapters), bf16-MFMA implementation.
// x: (197, 64, 768) fp32. b=8, T=8. Output fp32 same shape.
// ---------------------------------------------------------------------------

typedef __attribute__((ext_vector_type(8))) short bf16x8;
typedef __attribute__((ext_vector_type(4))) float f32x4;

__device__ __forceinline__ float bf2f(short s) {
  unsigned u = ((unsigned)(unsigned short)s) << 16;
  float f;
  __builtin_memcpy(&f, &u, 4);
  return f;
}
__device__ __forceinline__ short f2bf(float f) {
  __hip_bfloat16 h = __float2bfloat16(f);
  short s;
  __builtin_memcpy(&s, &h, 2);
  return s;
}

// async global->LDS, 16B per lane. lds ptr must be wave-uniform base.
__device__ __forceinline__ void gld16(void* lds, const void* g) {
  __builtin_amdgcn_global_load_lds(
      (const __attribute__((address_space(1))) unsigned int*)g,
      (__attribute__((address_space(3))) unsigned int*)lds, 16, 0, 0);
}

// ---------------------------------------------------------------------------
// Weight fp32 -> bf16 conversion (10 arrays in one kernel)
// ---------------------------------------------------------------------------
struct WPair { const float* s; short* d; int n; };
struct WArr { WPair p[10]; };

__global__ __launch_bounds__(256)
void convert_k(WArr a) {
  WPair w = a.p[blockIdx.y];
  for (int i = blockIdx.x * 256 + threadIdx.x; i < w.n; i += gridDim.x * 256)
    w.d[i] = f2bf(w.s[i]);
}

// concat bias: out[0..3071]=fc_b, out[3072..3263]=ma1_b, pad 0
__global__ __launch_bounds__(256)
void catf_k(const float* __restrict__ a, const float* __restrict__ b,
            float* __restrict__ o) {
  int i = blockIdx.x * 256 + threadIdx.x;
  if (i < 3328)
    o[i] = i < 3072 ? a[i] : (i < 3264 ? b[i - 3072] : 0.f);
}

// ---------------------------------------------------------------------------
// LayerNorm (per-token, 768): fp32 in -> bf16 out
// ---------------------------------------------------------------------------
__global__ __launch_bounds__(256)
void ln_k(const float* __restrict__ in, const float* __restrict__ g,
          const float* __restrict__ b, short* __restrict__ out) {
  const int t = blockIdx.x;
  const float* xr = in + (size_t)t * 768;
  const int tid = threadIdx.x;
  float v0 = xr[tid], v1 = xr[tid + 256], v2 = xr[tid + 512];
  float s = v0 + v1 + v2;
#pragma unroll
  for (int m = 1; m < 64; m <<= 1) s += __shfl_xor(s, m);
  __shared__ float red[4];
  if ((tid & 63) == 0) red[tid >> 6] = s;
  __syncthreads();
  float mu = (red[0] + red[1] + red[2] + red[3]) * (1.f / 768.f);
  __syncthreads();
  float d0 = v0 - mu, d1 = v1 - mu, d2 = v2 - mu;
  float q = d0 * d0 + d1 * d1 + d2 * d2;
#pragma unroll
  for (int m = 1; m < 64; m <<= 1) q += __shfl_xor(q, m);
  if ((tid & 63) == 0) red[tid >> 6] = q;
  __syncthreads();
  float rstd = rsqrtf((red[0] + red[1] + red[2] + red[3]) * (1.f / 768.f) + 1e-5f);
  size_t o = (size_t)t * 768;
  out[o + tid]       = f2bf(d0 * rstd * g[tid]       + b[tid]);
  out[o + tid + 256] = f2bf(d1 * rstd * g[tid + 256] + b[tid + 256]);
  out[o + tid + 512] = f2bf(d2 * rstd * g[tid + 512] + b[tid + 512]);
}

// ---------------------------------------------------------------------------
// Small-matrix GEMM (64x64 tiles): C = act(A @ W^T + bias), epilogues as below.
// ACT: 0 none, 1 QuickGELU, 2 exact GELU
// EPI: 0 bf16 out; 1 f32 out; 5 bf16 out = v*lam[row]
// ---------------------------------------------------------------------------
template <int ACT, int EPI>
__global__ __launch_bounds__(256)
void gemm_k(const short* __restrict__ A, int lda,
            const short* __restrict__ W,
            const float* __restrict__ bias,
            short* __restrict__ outb, float* __restrict__ outf,
            const float* __restrict__ lam,
            int M, int N, int K) {
  __shared__ short As[64][40];
  __shared__ short Ws[64][40];
  const int tid = threadIdx.x;
  const int n0 = blockIdx.x * 64;
  const int m0 = blockIdx.y * 64;
  const int lane = tid & 63, w = tid >> 6;
  const int wr = w >> 1, wc = w & 1;
  const int g = lane >> 4, li = lane & 15;
  const int srow = tid >> 2, scol = (tid & 3) * 8;

  f32x4 acc[2][2];
#pragma unroll
  for (int i = 0; i < 2; i++)
#pragma unroll
    for (int j = 0; j < 2; j++) acc[i][j] = (f32x4){0.f, 0.f, 0.f, 0.f};

  const short* Aptr = A + (size_t)(m0 + srow) * lda + scol;
  const short* Wptr = W + (size_t)(n0 + srow) * K + scol;

  for (int kk = 0; kk < K; kk += 32) {
    __syncthreads();
    *(bf16x8*)&As[srow][scol] = *(const bf16x8*)(Aptr + kk);
    *(bf16x8*)&Ws[srow][scol] = *(const bf16x8*)(Wptr + kk);
    __syncthreads();
    bf16x8 a[2], b[2];
#pragma unroll
    for (int mi = 0; mi < 2; ++mi)
      a[mi] = *(const bf16x8*)&As[wr * 32 + mi * 16 + li][g * 8];
#pragma unroll
    for (int ni = 0; ni < 2; ++ni)
      b[ni] = *(const bf16x8*)&Ws[wc * 32 + ni * 16 + li][g * 8];
#pragma unroll
    for (int mi = 0; mi < 2; ++mi)
#pragma unroll
      for (int ni = 0; ni < 2; ++ni)
        acc[mi][ni] = __builtin_amdgcn_mfma_f32_16x16x32_bf16(
            a[mi], b[ni], acc[mi][ni], 0, 0, 0);
  }

#pragma unroll
  for (int mi = 0; mi < 2; ++mi)
#pragma unroll
    for (int ni = 0; ni < 2; ++ni)
#pragma unroll
      for (int r = 0; r < 4; ++r) {
        int row = m0 + wr * 32 + mi * 16 + g * 4 + r;
        int col = n0 + wc * 32 + ni * 16 + li;
        float v = acc[mi][ni][r];
        if (bias) v += bias[col];
        if (ACT == 1) v = v / (1.f + __expf(-1.702f * v));
        if (ACT == 2) v = 0.5f * v * (1.f + erff(v * 0.70710678118f));
        size_t idx = (size_t)row * N + col;
        if (EPI == 0) outb[idx] = f2bf(v);
        else if (EPI == 1) outf[idx] = v;
        else if (EPI == 5) outb[idx] = f2bf(v * lam[row]);
      }
}

// ---------------------------------------------------------------------------
// Wide GEMM, 8 waves, 256x128 tile (4M x 2N wave grid, each wave 64x64,
// acc[4][4] -> 16 MFMA per K-step). BK=32, 2-buffer ring (48 KB), 3 gld16/
// thread/step (A x2, W x1), STAGE(t+1) before counted vmcnt(3).
// Conflict-free XOR swizzle + XCD swizzle. launch_bounds(512,4): 128 regs
// so acc (64 AGPR) fits without spill (R13 lesson). 2 blocks/CU.
// NW = W row count (may be < N tiles' span; staging rows clamp to NW-1).
// EPI 0: bf16 out to outb[N]. EPI 7 (fused fc+ma1): col<3072 -> quickgelu
// -> outb[row*3072+col]; 3072<=col<3264 -> exact gelu -> outb2[row*192+..];
// col>=3264 dropped.
// ---------------------------------------------------------------------------
template <int ACT, int EPI>
__global__ __launch_bounds__(512, 4)
void gemm256x128_k(const short* __restrict__ A, int lda,
                   const short* __restrict__ W,
                   const float* __restrict__ bias,
                   short* __restrict__ outb, short* __restrict__ outb2,
                   int M, int N, int NW, int K, int nx) {
  int nwg = gridDim.x;
  int orig = blockIdx.x;
  int q = nwg >> 3, r = nwg & 7;
  int xcd = orig & 7, cidx = orig >> 3;
  int wgid = (xcd < r ? xcd * (q + 1) : r * (q + 1) + (xcd - r) * q) + cidx;
  const int n0 = (wgid % nx) * 128;
  const int m0 = (wgid / nx) * 256;

  __shared__ short As[2][256][32];   // 32 KB
  __shared__ short Ws[2][128][32];   // 16 KB
  const int tid = threadIdx.x;
  const int w = tid >> 6, lane = tid & 63;
  const int g = lane >> 4, li = lane & 15;
  const int wr = w >> 1, wc = w & 1;     // 4M x 2N wave grid

  const int sgc = ((tid & 3) ^ ((tid >> 3) & 3)) * 8;   // pre-swizzled src chunk
  const int cxr = (g ^ ((li >> 1) & 3)) * 8;            // swizzled read chunk

  f32x4 acc[4][4];
#pragma unroll
  for (int i = 0; i < 4; i++)
#pragma unroll
    for (int j = 0; j < 4; j++) acc[i][j] = (f32x4){0.f, 0.f, 0.f, 0.f};

  int arj[2];
#pragma unroll
  for (int j = 0; j < 2; ++j) {
    int rA = m0 + j * 128 + (tid >> 2);
    arj[j] = rA > M - 1 ? M - 1 : rA;
  }
  int wrow = n0 + (tid >> 2);
  if (wrow > NW - 1) wrow = NW - 1;
  const short* Ap0 = A + (size_t)arj[0] * lda + sgc;
  const short* Ap1 = A + (size_t)arj[1] * lda + sgc;
  const short* Wp  = W + (size_t)wrow * K + sgc;

  const int total = K >> 5;

  auto STAGE = [&](int s, int bi) {
    const int kk = s * 32;
    gld16(&As[bi][w * 16][0],       Ap0 + kk);
    gld16(&As[bi][128 + w * 16][0], Ap1 + kk);
    gld16(&Ws[bi][w * 16][0],       Wp + kk);
  };

  STAGE(0, 0);

  for (int t = 0; t < total; ++t) {
    const int bi = t & 1;
    if (t + 1 < total) {
      STAGE(t + 1, bi ^ 1);
      asm volatile("s_waitcnt vmcnt(3)" ::: "memory");
    } else {
      asm volatile("s_waitcnt vmcnt(0)" ::: "memory");
    }
    __builtin_amdgcn_s_barrier();

    bf16x8 a[4], b[4];
#pragma unroll
    for (int mi = 0; mi < 4; ++mi)
      a[mi] = *(const bf16x8*)&As[bi][wr * 64 + mi * 16 + li][cxr];
#pragma unroll
    for (int ni = 0; ni < 4; ++ni)
      b[ni] = *(const bf16x8*)&Ws[bi][wc * 64 + ni * 16 + li][cxr];
    asm volatile("s_waitcnt lgkmcnt(0)" ::: "memory");
    __builtin_amdgcn_sched_barrier(0);
#pragma unroll
    for (int mi = 0; mi < 4; ++mi)
#pragma unroll
      for (int ni = 0; ni < 4; ++ni)
        acc[mi][ni] = __builtin_amdgcn_mfma_f32_16x16x32_bf16(
            a[mi], b[ni], acc[mi][ni], 0, 0, 0);
    __builtin_amdgcn_s_barrier();
  }

#pragma unroll
  for (int mi = 0; mi < 4; ++mi)
#pragma unroll
    for (int ni = 0; ni < 4; ++ni)
#pragma unroll
      for (int r = 0; r < 4; ++r) {
        int row = m0 + wr * 64 + mi * 16 + g * 4 + r;
        int col = n0 + wc * 64 + ni * 16 + li;
        if (row >= M) continue;
        float v = acc[mi][ni][r];
        if (EPI == 0) {
          if (bias) v += bias[col];
          if (ACT == 1) v = v / (1.f + __expf(-1.702f * v));
          outb[(size_t)row * N + col] = f2bf(v);
        } else {  // EPI == 7: fused fc(quickgelu) + ma1(gelu)
          if (col < 3072) {
            v += bias[col];
            v = v / (1.f + __expf(-1.702f * v));
            outb[(size_t)row * 3072 + col] = f2bf(v);
          } else if (col < 3264) {
            v += bias[col];
            v = 0.5f * v * (1.f + erff(v * 0.70710678118f));
            outb2[(size_t)row * 192 + (col - 3072)] = f2bf(v);
          }
        }
      }
}

// ---------------------------------------------------------------------------
// Big GEMM, 8-wave pipeline: 128x128 tile, 512 threads (2M x 4N, each wave
// 64x32 -> acc[4][2]), BK=32, 2-buffer ring (32 KB), STAGE(t+1) before
// counted vmcnt(2). Conflict-free XOR swizzle + XCD grid swizzle. Optional
// second GEMM. For grid-starved N=768 GEMMs (x1, proj: 594 blocks).
// EPI: 0 bf16 out; 2 x1 = resid + (1-lam[n])*v + addv; 6 f32 out = resid + v
// ---------------------------------------------------------------------------
template <int ACT, int EPI>
__global__ __launch_bounds__(512, 6)
void gemm512_k(const short* __restrict__ A, int lda,
               const short* __restrict__ W,
               const float* __restrict__ bias,
               short* __restrict__ outb, float* __restrict__ outf,
               const float* __restrict__ lam,
               const float* __restrict__ addv,
               const float* __restrict__ resid,
               const short* __restrict__ A2, int lda2,
               const short* __restrict__ W2,
               const float* __restrict__ bias2, int K2,
               int M, int N, int K, int nx) {
  int nwg = gridDim.x;
  int orig = blockIdx.x;
  int q = nwg >> 3, r = nwg & 7;
  int xcd = orig & 7, cidx = orig >> 3;
  int wgid = (xcd < r ? xcd * (q + 1) : r * (q + 1) + (xcd - r) * q) + cidx;
  const int n0 = (wgid % nx) * 128;
  const int m0 = (wgid / nx) * 128;

  __shared__ short As[2][128][32];
  __shared__ short Ws[2][128][32];
  const int tid = threadIdx.x;
  const int w = tid >> 6, lane = tid & 63;
  const int g = lane >> 4, li = lane & 15;
  const int wr = w >> 2, wc = w & 3;          // 2M x 4N wave grid

  const int srow = tid >> 2;                                  // 0..127
  const int scol = ((tid & 3) ^ ((tid >> 3) & 3)) * 8;        // pre-swizzled src
  const int cxr  = (g ^ ((li >> 1) & 3)) * 8;                 // swizzled read

  f32x4 acc[4][2];
#pragma unroll
  for (int i = 0; i < 4; i++)
#pragma unroll
    for (int j = 0; j < 2; j++) acc[i][j] = (f32x4){0.f, 0.f, 0.f, 0.f};

  int ar = m0 + srow; if (ar > M - 1) ar = M - 1;
  const short* Ap = A + (size_t)ar * lda + scol;
  const short* Wp = W + (size_t)(n0 + srow) * K + scol;
  const short* A2b = A2 ? A2 : A;
  const short* W2b = W2 ? W2 : W;
  const short* Bp = A2b + (size_t)ar * lda2 + scol;
  const short* Vp = W2b + (size_t)(n0 + srow) * K2 + scol;

  const int ks1 = K >> 5;
  const int ks2 = A2 ? (K2 >> 5) : 0;
  const int total = ks1 + ks2;

  auto STAGE = [&](int s, int bi) {
    if (s < ks1) {
      const int kk = s * 32;
      gld16(&As[bi][w * 16][0], Ap + kk);
      gld16(&Ws[bi][w * 16][0], Wp + kk);
    } else {
      const int kk = (s - ks1) * 32;
      gld16(&As[bi][w * 16][0], Bp + kk);
      gld16(&Ws[bi][w * 16][0], Vp + kk);
    }
  };

  STAGE(0, 0);

  for (int t = 0; t < total; ++t) {
    const int bi = t & 1;
    if (t + 1 < total) {
      STAGE(t + 1, bi ^ 1);
      asm volatile("s_waitcnt vmcnt(2)" ::: "memory");
    } else {
      asm volatile("s_waitcnt vmcnt(0)" ::: "memory");
    }
    __builtin_amdgcn_s_barrier();

    bf16x8 a[4], b[2];
#pragma unroll
    for (int mi = 0; mi < 4; ++mi)
      a[mi] = *(const bf16x8*)&As[bi][wr * 64 + mi * 16 + li][cxr];
#pragma unroll
    for (int ni = 0; ni < 2; ++ni)
      b[ni] = *(const bf16x8*)&Ws[bi][wc * 32 + ni * 16 + li][cxr];
    asm volatile("s_waitcnt lgkmcnt(0)" ::: "memory");
    __builtin_amdgcn_sched_barrier(0);
#pragma unroll
    for (int mi = 0; mi < 4; ++mi)
#pragma unroll
      for (int ni = 0; ni < 2; ++ni)
        acc[mi][ni] = __builtin_amdgcn_mfma_f32_16x16x32_bf16(
            a[mi], b[ni], acc[mi][ni], 0, 0, 0);
    __builtin_amdgcn_s_barrier();
  }

#pragma unroll
  for (int mi = 0; mi < 4; ++mi)
#pragma unroll
    for (int ni = 0; ni < 2; ++ni)
#pragma unroll
      for (int r = 0; r < 4; ++r) {
        int row = m0 + wr * 64 + mi * 16 + g * 4 + r;
        int col = n0 + wc * 32 + ni * 16 + li;
        if (row >= M) continue;
        float v = acc[mi][ni][r];
        if (bias) v += bias[col];
        if (bias2) v += bias2[col];
        if (ACT == 1) v = v / (1.f + __expf(-1.702f * v));
        if (ACT == 2) v = 0.5f * v * (1.f + erff(v * 0.70710678118f));
        size_t idx = (size_t)row * N + col;
        if (EPI == 0) outb[idx] = f2bf(v);
        else if (EPI == 2) {
          float l = lam[row & 63];
          outf[idx] = resid[idx] + (1.f - l) * v + addv[(size_t)(row & 63) * 768 + col];
        } else if (EPI == 6) outf[idx] = resid[idx] + v;
      }
}

// ---------------------------------------------------------------------------
// Main attention (per n,h): softmax(Q K^T / 8) V, Tx=Ty=197, hd=64.
// qkv layout: [token = p*64+n][2304], q|k|v at +0,+768,+1536, head h at h*64.
// ---------------------------------------------------------------------------
__global__ __launch_bounds__(256)
void attn_k(const short* __restrict__ qkv, short* __restrict__ attn_out) {
  const int n = blockIdx.x;
  const int h = blockIdx.y;
  const int tid = threadIdx.x;
  const int lane = tid & 63, w = tid >> 6;
  const int g = lane >> 4, li = lane & 15;

  __shared__ short Vt[64][232];       // V^T [d][key], keys 0..223 (zero pad)
  __shared__ short Pl[4][16][232];    // per-wave P tile [qrow][key]

  {
    const int d = tid & 63;
    for (int key = tid >> 6; key < 224; key += 4) {
      short v = 0;
      if (key < 197)
        v = qkv[(size_t)(key * 64 + n) * 2304 + 1536 + h * 64 + d];
      Vt[d][key] = v;
    }
  }
  __syncthreads();

  const short* Qb = qkv + (size_t)n * 2304 + h * 64;
  const short* Kb = Qb + 768;

  for (int mt = w; mt < 13; mt += 4) {
    const int m0 = mt * 16;
    int arow = m0 + li;
    if (arow > 196) arow = 196;
    bf16x8 a0 = *(const bf16x8*)(Qb + (size_t)arow * 147456 + g * 8);
    bf16x8 a1 = *(const bf16x8*)(Qb + (size_t)arow * 147456 + 32 + g * 8);

    float s[13][4];
#pragma unroll
    for (int nt = 0; nt < 13; ++nt) {
      int kc = nt * 16 + li;
      if (kc > 196) kc = 196;
      bf16x8 b0 = *(const bf16x8*)(Kb + (size_t)kc * 147456 + g * 8);
      bf16x8 b1 = *(const bf16x8*)(Kb + (size_t)kc * 147456 + 32 + g * 8);
      f32x4 acc = (f32x4){0.f, 0.f, 0.f, 0.f};
      acc = __builtin_amdgcn_mfma_f32_16x16x32_bf16(a0, b0, acc, 0, 0, 0);
      acc = __builtin_amdgcn_mfma_f32_16x16x32_bf16(a1, b1, acc, 0, 0, 0);
#pragma unroll
      for (int r = 0; r < 4; ++r) s[nt][r] = acc[r] * 0.125f;
    }

    // row-wise softmax (rows live in 16-lane groups; reduce via shfl_xor)
#pragma unroll
    for (int r = 0; r < 4; ++r) {
      float mx = -1e30f;
#pragma unroll
      for (int nt = 0; nt < 13; ++nt) {
        if (nt * 16 + li >= 197) s[nt][r] = -1e30f;
        mx = fmaxf(mx, s[nt][r]);
      }
      mx = fmaxf(mx, __shfl_xor(mx, 1));
      mx = fmaxf(mx, __shfl_xor(mx, 2));
      mx = fmaxf(mx, __shfl_xor(mx, 4));
      mx = fmaxf(mx, __shfl_xor(mx, 8));
      float sum = 0.f;
#pragma unroll
      for (int nt = 0; nt < 13; ++nt) {
        float e = (s[nt][r] <= -1e29f) ? 0.f : __expf(s[nt][r] - mx);
        s[nt][r] = e;
        sum += e;
      }
      sum += __shfl_xor(sum, 1);
      sum += __shfl_xor(sum, 2);
      sum += __shfl_xor(sum, 4);
      sum += __shfl_xor(sum, 8);
      float inv = 1.f / sum;
#pragma unroll
      for (int nt = 0; nt < 13; ++nt) s[nt][r] *= inv;
    }

    // write P tile (bf16) into this wave's LDS region
#pragma unroll
    for (int r = 0; r < 4; ++r) {
      int row = g * 4 + r;
#pragma unroll
      for (int nt = 0; nt < 13; ++nt)
        Pl[w][row][nt * 16 + li] = f2bf(s[nt][r]);
      Pl[w][row][208 + li] = 0;
    }
    asm volatile("s_waitcnt lgkmcnt(0)" ::: "memory");
    __builtin_amdgcn_sched_barrier(0);

    // PV: O(16x64) = P(16x224) @ V(224x64)
    f32x4 o[4];
#pragma unroll
    for (int ni = 0; ni < 4; ++ni) o[ni] = (f32x4){0.f, 0.f, 0.f, 0.f};
#pragma unroll
    for (int kk = 0; kk < 7; ++kk) {
      bf16x8 pa = *(const bf16x8*)&Pl[w][li][kk * 32 + g * 8];
#pragma unroll
      for (int ni = 0; ni < 4; ++ni) {
        bf16x8 vb = *(const bf16x8*)&Vt[ni * 16 + li][kk * 32 + g * 8];
        o[ni] = __builtin_amdgcn_mfma_f32_16x16x32_bf16(pa, vb, o[ni], 0, 0, 0);
      }
    }
#pragma unroll
    for (int ni = 0; ni < 4; ++ni)
#pragma unroll
      for (int r = 0; r < 4; ++r) {
        int prow = m0 + g * 4 + r;
        if (prow < 197)
          attn_out[(size_t)(prow * 64 + n) * 768 + h * 64 + ni * 16 + li] =
              f2bf(o[ni][r]);
      }
  }
}

// ---------------------------------------------------------------------------
// lam partial: block (n, mt) computes sum_{p in tile, k<197} exp((Q_p.K_k)/8)
// over the full 768-dim dot, writes eo_part[n*13+mt]. No atomics.
// ---------------------------------------------------------------------------
__global__ __launch_bounds__(256)
void lam_part_k(const short* __restrict__ qkv, float* __restrict__ eo_part) {
  const int n = blockIdx.x;
  const int mt = blockIdx.y;
  const int tid = threadIdx.x;
  const int lane = tid & 63, w = tid >> 6;
  const int g = lane >> 4, li = lane & 15;
  const short* Qb = qkv + (size_t)n * 2304;
  const short* Kb = Qb + 768;

  int arow = mt * 16 + li;
  if (arow > 196) arow = 196;
  const short* Ap = Qb + (size_t)arow * 147456;

  // hoist A fragments (24 x bf16x8)
  bf16x8 a[24];
#pragma unroll
  for (int s = 0; s < 24; ++s)
    a[s] = *(const bf16x8*)(Ap + s * 32 + g * 8);

  float eo = 0.f;
  for (int nt = w; nt < 13; nt += 4) {
    int kc = nt * 16 + li;
    if (kc > 196) kc = 196;
    const short* Bp = Kb + (size_t)kc * 147456;
    f32x4 acc = (f32x4){0.f, 0.f, 0.f, 0.f};
#pragma unroll
    for (int s = 0; s < 24; ++s) {
      bf16x8 b = *(const bf16x8*)(Bp + s * 32 + g * 8);
      acc = __builtin_amdgcn_mfma_f32_16x16x32_bf16(a[s], b, acc, 0, 0, 0);
    }
#pragma unroll
    for (int r = 0; r < 4; ++r) {
      int prow = mt * 16 + g * 4 + r;
      int col = nt * 16 + li;
      if (prow < 197 && col < 197) eo += __expf(acc[r] * 0.125f);
    }
  }

#pragma unroll
  for (int m = 1; m < 64; m <<= 1) eo += __shfl_xor(eo, m);
  __shared__ float red[4];
  if (lane == 0) red[w] = eo;
  __syncthreads();
  if (tid == 0)
    eo_part[n * 13 + mt] = red[0] + red[1] + red[2] + red[3];
}

// ---------------------------------------------------------------------------
// lam finalize: per n, ec = sum_p exp((Q_p . kt_n)/8); lam = ec/(ec+eo)
// ---------------------------------------------------------------------------
__global__ __launch_bounds__(64)
void lam_fin_k(const short* __restrict__ qkv, const short* __restrict__ kvt,
               const float* __restrict__ eo_part, float* __restrict__ lam) {
  const int n = blockIdx.x;
  const int lane = threadIdx.x;
  const short* kt = kvt + (size_t)n * 1536;

  float ec = 0.f;
  for (int p = lane; p < 197; p += 64) {
    const short* qp = qkv + (size_t)n * 2304 + (size_t)p * 147456;
    float dot = 0.f;
    for (int d0 = 0; d0 < 768; d0 += 8) {
      bf16x8 qa = *(const bf16x8*)(qp + d0);
      bf16x8 ka = *(const bf16x8*)(kt + d0);
#pragma unroll
      for (int j = 0; j < 8; ++j) dot += bf2f(qa[j]) * bf2f(ka[j]);
    }
    ec += __expf(dot * 0.125f);
  }
#pragma unroll
  for (int m = 1; m < 64; m <<= 1) ec += __shfl_xor(ec, m);

  if (lane == 0) {
    float eo = 0.f;
#pragma unroll
    for (int t = 0; t < 13; ++t) eo += eo_part[n * 13 + t];
    lam[n] = ec / (ec + eo);
  }
}

// ---------------------------------------------------------------------------
// Temporal attention on class token: per (bb,h), 8x8 scores over qkv rows 0..63
// ---------------------------------------------------------------------------
__global__ __launch_bounds__(64)
void tattn_k(const short* __restrict__ qkv, short* __restrict__ attn_t) {
  const int bb = blockIdx.x, h = blockIdx.y;
  const int tid = threadIdx.x;
  __shared__ float sm[8][9];
  {
    const int tt = tid >> 3, ss = tid & 7;
    const short* q = qkv + (size_t)(bb * 8 + tt) * 2304 + h * 64;
    const short* k = qkv + (size_t)(bb * 8 + ss) * 2304 + 768 + h * 64;
    float dot = 0.f;
#pragma unroll
    for (int d = 0; d < 64; d += 8) {
      bf16x8 qa = *(const bf16x8*)(q + d);
      bf16x8 ka = *(const bf16x8*)(k + d);
#pragma unroll
      for (int j = 0; j < 8; ++j) dot += bf2f(qa[j]) * bf2f(ka[j]);
    }
    sm[tt][ss] = dot * 0.125f;
  }
  __syncthreads();
  if (tid < 8) {
    float mx = -1e30f;
#pragma unroll
    for (int s2 = 0; s2 < 8; ++s2) mx = fmaxf(mx, sm[tid][s2]);
    float sum = 0.f;
#pragma unroll
    for (int s2 = 0; s2 < 8; ++s2) {
      float e = __expf(sm[tid][s2] - mx);
      sm[tid][s2] = e;
      sum += e;
    }
    float inv = 1.f / sum;
#pragma unroll
    for (int s2 = 0; s2 < 8; ++s2) sm[tid][s2] *= inv;
  }
  __syncthreads();
  {
    const int d = tid;
    float v[8];
#pragma unroll
    for (int s2 = 0; s2 < 8; ++s2)
      v[s2] = bf2f(qkv[(size_t)(bb * 8 + s2) * 2304 + 1536 + h * 64 + d]);
#pragma unroll
    for (int tt = 0; tt < 8; ++tt) {
      float o = 0.f;
#pragma unroll
      for (int s2 = 0; s2 < 8; ++s2) o += sm[tt][s2] * v[s2];
      attn_t[(size_t)(bb * 8 + tt) * 768 + h * 64 + d] = f2bf(o);
    }
  }
}

// ---------------------------------------------------------------------------
// Host launch
// ---------------------------------------------------------------------------
extern "C" void kernel_launch(void* const* d_in, const int* in_sizes, int n_in,
                              void* d_out, int out_size, void* d_ws,
                              size_t ws_size, hipStream_t stream) {
  (void)in_sizes; (void)n_in; (void)out_size; (void)ws_size;

  const float* x          = (const float*)d_in[0];
  const float* in_proj_w  = (const float*)d_in[1];
  const float* in_proj_b  = (const float*)d_in[2];
  const float* out_proj_w = (const float*)d_in[3];
  const float* out_proj_b = (const float*)d_in[4];
  const float* ln1_g      = (const float*)d_in[5];
  const float* ln1_b      = (const float*)d_in[6];
  const float* ln2_g      = (const float*)d_in[7];
  const float* ln2_b      = (const float*)d_in[8];
  const float* fc_w       = (const float*)d_in[9];
  const float* fc_b       = (const float*)d_in[10];
  const float* proj_w     = (const float*)d_in[11];
  const float* proj_b     = (const float*)d_in[12];
  const float* sa1_w      = (const float*)d_in[13];
  const float* sa1_b      = (const float*)d_in[14];
  const float* sa2_w      = (const float*)d_in[15];
  const float* sa2_b      = (const float*)d_in[16];
  const float* ta1_w      = (const float*)d_in[17];
  const float* ta1_b      = (const float*)d_in[18];
  const float* ta2_w      = (const float*)d_in[19];
  const float* ta2_b      = (const float*)d_in[20];
  const float* ma1_w      = (const float*)d_in[21];
  const float* ma1_b      = (const float*)d_in[22];
  const float* ma2_w      = (const float*)d_in[23];
  const float* ma2_b      = (const float*)d_in[24];

  char* ws = (char*)d_ws;
  short* xln  = (short*)(ws + 0);           // 12608x768 bf16
  short* qkv  = (short*)(ws + 19365888);    // 12608x2304 bf16
  short* hbuf = (short*)(ws + 0);           // 12608x3072 bf16 (overlays xln+qkv)
  short* attn = (short*)(ws + 77463552);    // 12608x768 bf16
  short* h2   = (short*)(ws + 77463552);    // 12608x192 bf16 (overlays attn)
  float* x1   = (float*)(ws + 96829440);    // 12608x768 f32
  short* xn   = (short*)(ws + 135561216);   // 12608x768 bf16

  // weight region — offsets recomputed after w_fcma growth (R16 bug: w_proj
  // started 1024 B before w_fcma's end, corrupting ma1's last row)
  char* wreg = ws + 154927104;
  short* w_inproj  = (short*)(wreg + 0);         // 2304x768 -> 3538944 B
  short* w_outproj = (short*)(wreg + 3538944);   //  768x768 -> 1179648 B
  short* w_fcma    = (short*)(wreg + 4718592);   // 3264x768 -> 5013504 B
  short* w_proj    = (short*)(wreg + 9732096);   // 768x3072 -> 4718592 B
  short* w_sa1     = (short*)(wreg + 14450688);  //  192x768 ->  294912 B
  short* w_sa2     = (short*)(wreg + 14745600);
  short* w_ta1     = (short*)(wreg + 15040512);
  short* w_ta2     = (short*)(wreg + 15335424);
  short* w_ma2     = (short*)(wreg + 15630336);
  float* cbias     = (float*)(wreg + 15925248);  // 3328 f32 -> 13312 B

  char* sm = ws + 171966464;                // past wreg end (170865664)
  short* attn_t  = (short*)(sm + 0);
  short* tproj   = (short*)(sm + 98304);
  short* th      = (short*)(sm + 196608);
  short* xt_out  = (short*)(sm + 221184);
  short* kv_t    = (short*)(sm + 319488);
  short* a_in    = (short*)(sm + 516096);
  short* sa_h    = (short*)(sm + 614400);
  float* sa_out  = (float*)(sm + 638976);
  float* lam     = (float*)(sm + 835584);
  float* eo_part = (float*)(sm + 835840);   // 64*13 floats

  float* out = (float*)d_out;

  // 0. weights -> bf16 (fc and ma1 go into one concatenated buffer)
  WArr arr;
  arr.p[0] = {in_proj_w,  w_inproj,            2304 * 768};
  arr.p[1] = {out_proj_w, w_outproj,           768 * 768};
  arr.p[2] = {fc_w,       w_fcma,              3072 * 768};
  arr.p[3] = {proj_w,     w_proj,              768 * 3072};
  arr.p[4] = {sa1_w,      w_sa1,               192 * 768};
  arr.p[5] = {sa2_w,      w_sa2,               768 * 192};
  arr.p[6] = {ta1_w,      w_ta1,               192 * 768};
  arr.p[7] = {ta2_w,      w_ta2,               768 * 192};
  arr.p[8] = {ma1_w,      w_fcma + 3072 * 768, 192 * 768};
  arr.p[9] = {ma2_w,      w_ma2,               768 * 192};
  convert_k<<<dim3(128, 10), 256, 0, stream>>>(arr);
  catf_k<<<13, 256, 0, stream>>>(fc_b, ma1_b, cbias);

  // 1. LN1(x) -> xln
  ln_k<<<12608, 256, 0, stream>>>(x, ln1_g, ln1_b, xln);

  // 2. qkv = xln @ in_proj^T + b   (12608 x 2304), 256x128 tiles
  gemm256x128_k<0, 0><<<50 * 18, 512, 0, stream>>>(
      xln, 768, w_inproj, in_proj_b, qkv, nullptr, 12608, 2304, 2304, 768, 18);

  // 3. lam partial sums (needs qkv only)
  lam_part_k<<<dim3(64, 13), 256, 0, stream>>>(qkv, eo_part);

  // 4. temporal attention on class token (uses qkv rows 0..63)
  tattn_k<<<dim3(8, 12), 64, 0, stream>>>(qkv, attn_t);

  // 5. tproj = attn_t @ out_proj^T + b
  gemm_k<0, 0><<<dim3(12, 1), 256, 0, stream>>>(
      attn_t, 768, w_outproj, out_proj_b, tproj, nullptr, nullptr, 64, 768, 768);
  // 6. th = gelu(tproj @ ta1^T + b)
  gemm_k<2, 0><<<dim3(3, 1), 256, 0, stream>>>(
      tproj, 768, w_ta1, ta1_b, th, nullptr, nullptr, 64, 192, 768);
  // 7. xt_out = th @ ta2^T + b
  gemm_k<0, 0><<<dim3(12, 1), 256, 0, stream>>>(
      th, 192, w_ta2, ta2_b, xt_out, nullptr, nullptr, 64, 768, 192);
  // 8. kv_t = xt_out @ in_proj[768:2304]^T + b[768:2304]  (64 x 1536)
  gemm_k<0, 0><<<dim3(24, 1), 256, 0, stream>>>(
      xt_out, 768, w_inproj + 768 * 768, in_proj_b + 768, kv_t, nullptr,
      nullptr, 64, 1536, 768);

  // 9. main attention -> attn (pre out-proj)
  attn_k<<<dim3(64, 12), 256, 0, stream>>>(qkv, attn);

  // 10. lam finalize (needs kv_t + eo_part)
  lam_fin_k<<<64, 64, 0, stream>>>(qkv, kv_t, eo_part, lam);

  // 11. a_in = lam * (v_t @ out_proj^T + b)
  gemm_k<0, 5><<<dim3(12, 1), 256, 0, stream>>>(
      kv_t + 768, 1536, w_outproj, out_proj_b, a_in, nullptr, lam, 64, 768, 768);
  // 12. sa_h = gelu(a_in @ sa1^T + b)
  gemm_k<2, 0><<<dim3(3, 1), 256, 0, stream>>>(
      a_in, 768, w_sa1, sa1_b, sa_h, nullptr, nullptr, 64, 192, 768);
  // 13. sa_out = sa_h @ sa2^T + b (f32)
  gemm_k<0, 1><<<dim3(12, 1), 256, 0, stream>>>(
      sa_h, 192, w_sa2, sa2_b, nullptr, sa_out, nullptr, 64, 768, 192);

  // 14. x1 = x + (1-lam)*(attn @ out_proj^T + b) + sa_out[n]
  gemm512_k<0, 2><<<6 * 99, 512, 0, stream>>>(
      attn, 768, w_outproj, out_proj_b, nullptr, x1, lam, sa_out, x,
      nullptr, 0, nullptr, nullptr, 32, 12608, 768, 768, 6);

  // 15. LN2(x1) -> xn
  ln_k<<<12608, 256, 0, stream>>>(x1, ln2_g, ln2_b, xn);

  // 16. fused: h = quickgelu(xn @ fc^T + b) AND h2 = gelu(xn @ ma1^T + b)
  //     one GEMM over concatenated weights (N-span 3328, NW 3264)
  gemm256x128_k<1, 7><<<50 * 26, 512, 0, stream>>>(
      xn, 768, w_fcma, cbias, hbuf, h2, 12608, 3328, 3264, 768, 26);

  // 17. out = x1 + h @ proj^T + h2 @ ma2^T + proj_b + ma2_b  (fused dual-K)
  gemm512_k<0, 6><<<6 * 99, 512, 0, stream>>>(
      hbuf, 3072, w_proj, proj_b, nullptr, out, nullptr, nullptr, x1,
      h2, 192, w_ma2, ma2_b, 192, 12608, 768, 3072, 6);
}